// Round 9
// baseline (449.595 us; speedup 1.0000x reference)
//
#include <hip/hip_runtime.h>
#include <hip/hip_bf16.h>
#include <math.h>

constexpr int KN  = 100;            // K (multi_factor * top_k)
constexpr int DE  = 64;             // embedding dim
constexpr int CAT = 2 * KN * DE;    // 12800
constexpr int HID = 128;
constexpr int CHUNK = 4096;         // rows per pipeline chunk: xb chunk 105MB
                                    // + tables 49MB + w1t 3.3MB < 256MB L3

typedef __bf16          bf16x8   __attribute__((ext_vector_type(8)));
typedef float           f32x4    __attribute__((ext_vector_type(4)));
typedef unsigned short  ushort8v __attribute__((ext_vector_type(8)));
typedef unsigned short  ushort4v __attribute__((ext_vector_type(4)));

static __device__ __forceinline__ unsigned short f2bf(float f) {
    __hip_bfloat16 h = __float2bfloat16(f);
    return *reinterpret_cast<unsigned short*>(&h);
}

static __device__ __forceinline__ bf16x8 mk_frag(ushort4v lo, ushort4v hi) {
    union { ushort8v u; bf16x8 b; } c;
    c.u = (ushort8v){ lo[0], lo[1], lo[2], lo[3], hi[0], hi[1], hi[2], hi[3] };
    return c.b;
}

// ---------------------------------------------------------------------------
// prep: 4 fp32->bf16 table conversions in one launch (blockIdx.y = segment)
// ---------------------------------------------------------------------------
__global__ __launch_bounds__(256) void cvt4(
    const float* __restrict__ a0, unsigned short* __restrict__ o0, int n0,
    const float* __restrict__ a1, unsigned short* __restrict__ o1, int n1,
    const float* __restrict__ a2, unsigned short* __restrict__ o2, int n2,
    const float* __restrict__ a3, unsigned short* __restrict__ o3, int n3)
{
    const float* in; unsigned short* out; int n4;
    switch (blockIdx.y) {
        case 0:  in = a0; out = o0; n4 = n0; break;
        case 1:  in = a1; out = o1; n4 = n1; break;
        case 2:  in = a2; out = o2; n4 = n2; break;
        default: in = a3; out = o3; n4 = n3; break;
    }
    for (int i = blockIdx.x * 256 + threadIdx.x; i < n4; i += gridDim.x * 256) {
        float4 v = ((const float4*)in)[i];
        ushort4v o = { f2bf(v.x), f2bf(v.y), f2bf(v.z), f2bf(v.w) };
        ((ushort4v*)out)[i] = o;
    }
}

// ---------------------------------------------------------------------------
// prep: w1t[n][k] = bf16(W1[k][n]) (unchanged, known-good)
// ---------------------------------------------------------------------------
__global__ __launch_bounds__(256) void prep_w1t(
    const float* __restrict__ W1, unsigned short* __restrict__ w1t)
{
    __shared__ unsigned short T[HID][72];
    const int t  = threadIdx.x;
    const int k0 = blockIdx.x * 64;

    for (int idx = t; idx < 64 * HID; idx += 256) {
        int kk = idx >> 7, n = idx & 127;
        T[n][kk] = f2bf(W1[(size_t)(k0 + kk) * HID + n]);
    }
    __syncthreads();
    for (int idx = t; idx < HID * 16; idx += 256) {
        int n = idx >> 4, c4 = idx & 15;
        *(ushort4v*)&w1t[(size_t)n * CAT + k0 + c4 * 4] =
            *(const ushort4v*)&T[n][c4 * 4];
    }
}

// ---------------------------------------------------------------------------
// Kernel 1 (unchanged — proven ~62us/chunk with L3-resident tables):
// S fragments global->register, E LDS-staged, regular xb stores.
// ---------------------------------------------------------------------------
__global__ __launch_bounds__(256) void einsum_mfma(
    const int* __restrict__ u_idx, const int* __restrict__ i_idx,
    const int* __restrict__ u_nbt, const int* __restrict__ i_nbt,
    const unsigned short* __restrict__ u_scr, const unsigned short* __restrict__ i_scr,
    const unsigned short* __restrict__ u_emb, const unsigned short* __restrict__ i_emb,
    unsigned short* __restrict__ xb, int b0)
{
    __shared__ __align__(16) unsigned short ET[64][136];  // 17.4 KB; reused as D-bounce
    __shared__ int nb[KN];

    const int t    = threadIdx.x;
    const int side = blockIdx.y;
    const int b    = b0 + blockIdx.x;

    const int*            idxs = side ? i_idx : u_idx;
    const int*            nbt  = side ? i_nbt : u_nbt;
    const unsigned short* scr  = side ? i_scr : u_scr;
    const unsigned short* emb  = side ? i_emb : u_emb;

    const ushort4v z4 = {0, 0, 0, 0};

    const int center = idxs[b];
    if (t < KN) nb[t] = nbt[(size_t)center * KN + t];

    for (int idx = t; idx < 64 * 7; idx += 256) {
        int r = idx / 7, c = idx - r * 7;
        *(ushort4v*)&ET[r][100 + c * 4] = z4;
    }
    __syncthreads();                           // nb ready

    for (int idx = t; idx < 25 * 16; idx += 256) {
        int d4 = idx / 25, j0 = idx - d4 * 25;
        ushort4v v0 = *(const ushort4v*)(emb + (size_t)nb[j0 * 4 + 0] * DE + d4 * 4);
        ushort4v v1 = *(const ushort4v*)(emb + (size_t)nb[j0 * 4 + 1] * DE + d4 * 4);
        ushort4v v2 = *(const ushort4v*)(emb + (size_t)nb[j0 * 4 + 2] * DE + d4 * 4);
        ushort4v v3 = *(const ushort4v*)(emb + (size_t)nb[j0 * 4 + 3] * DE + d4 * 4);
        ushort4v o0 = { v0[0], v1[0], v2[0], v3[0] };
        ushort4v o1 = { v0[1], v1[1], v2[1], v3[1] };
        ushort4v o2 = { v0[2], v1[2], v2[2], v3[2] };
        ushort4v o3 = { v0[3], v1[3], v2[3], v3[3] };
        *(ushort4v*)&ET[d4 * 4 + 0][j0 * 4] = o0;
        *(ushort4v*)&ET[d4 * 4 + 1][j0 * 4] = o1;
        *(ushort4v*)&ET[d4 * 4 + 2][j0 * 4] = o2;
        *(ushort4v*)&ET[d4 * 4 + 3][j0 * 4] = o3;
    }
    __syncthreads();

    const int w  = t >> 6;
    const int l  = t & 63;
    const int cl = l & 15;
    const int rg = l >> 4;

    const unsigned short* srow[7];
    #pragma unroll
    for (int mt = 0; mt < 7; ++mt) {
        int kr = mt * 16 + cl;
        if (kr > KN - 1) kr = KN - 1;
        srow[mt] = scr + (size_t)nb[kr] * KN;
    }

    f32x4 acc[7];
    #pragma unroll
    for (int m = 0; m < 7; ++m) acc[m] = (f32x4){0.f, 0.f, 0.f, 0.f};

    #pragma unroll
    for (int ks = 0; ks < 4; ++ks) {
        const int k0 = ks * 32 + rg * 8;
        bf16x8 bfrag = *(const bf16x8*)&ET[w * 16 + cl][k0];
        #pragma unroll
        for (int mt = 0; mt < 7; ++mt) {
            ushort4v lo, hi;
            if (ks < 3) {
                lo = *(const ushort4v*)(srow[mt] + k0);
                hi = *(const ushort4v*)(srow[mt] + k0 + 4);
            } else if (rg == 0) {
                lo = *(const ushort4v*)(srow[mt] + 96);
                hi = z4;
            } else {
                lo = z4; hi = z4;
            }
            bf16x8 afrag = mk_frag(lo, hi);
            acc[mt] = __builtin_amdgcn_mfma_f32_16x16x32_bf16(afrag, bfrag, acc[mt], 0, 0, 0);
        }
    }
    __syncthreads();

    unsigned short* X = &ET[0][0];
    #pragma unroll
    for (int mt = 0; mt < 7; ++mt) {
        #pragma unroll
        for (int rr = 0; rr < 4; ++rr) {
            int k = mt * 16 + rg * 4 + rr;
            if (k < KN) X[k * 72 + w * 16 + cl] = f2bf(acc[mt][rr]);
        }
    }
    __syncthreads();

    unsigned short* xr = xb + (size_t)blockIdx.x * CAT + side * (KN * DE);
    for (int idx = t; idx < KN * 8; idx += 256) {
        int r = idx >> 3, c8 = idx & 7;
        *(ushort8v*)&xr[r * DE + c8 * 8] = *(const ushort8v*)&X[r * 72 + c8 * 8];
    }
}

// ---------------------------------------------------------------------------
// Kernel 2 (v9): col-split MLP partials.
// Grid (rows/32, 4 col-quarters), 256 threads = 4 waves = 2 row-tiles x
// 2 col-tiles (block = 32 rows x 32 cols).  B-fragments DIRECT global->reg
// from L2-resident w1t (no Bt LDS!), register-double-buffered one K-step
// ahead.  A staged in LDS dbuf, BK=256 (50 steps).  relu is per-col so
// col-split partials p_q = sum_col relu(x.W1+b1)*W2 are exact; a tiny
// combine kernel finishes b2/relu/sigmoid.
// ---------------------------------------------------------------------------
__global__ __launch_bounds__(256) void mlp_partial(
    const unsigned short* __restrict__ xb, const unsigned short* __restrict__ w1t,
    const float* __restrict__ b1, const float* __restrict__ W2,
    float* __restrict__ pq, int b0, int bstride)
{
    __shared__ unsigned short A[2][32][264];  // 33.8 KB (BK=256 + 8 pad)
    __shared__ float red[4][16];

    const int t  = threadIdx.x;
    const int w  = t >> 6;
    const int l  = t & 63;
    const int cl = l & 15;
    const int rg = l >> 4;
    const int rt = w & 1;          // row-tile (16 rows)
    const int ct = w >> 1;         // col-tile (16 cols)
    const int q  = blockIdx.y;
    const int row0 = blockIdx.x * 32;
    const int col  = q * 32 + ct * 16 + cl;

    const unsigned short* brow = w1t + (size_t)col * CAT;

    auto stageA = [&](int buf, int kb) {
        #pragma unroll
        for (int i = 0; i < 4; ++i) {
            int c = t + i * 256;
            int r = c >> 5, c32 = c & 31;
            *(ushort8v*)&A[buf][r][c32 * 8] =
                *(const ushort8v*)&xb[(size_t)(row0 + r) * CAT + kb + c32 * 8];
        }
    };

    f32x4 acc = (f32x4){0.f, 0.f, 0.f, 0.f};
    bf16x8 bcur[8], bnxt[8];

    stageA(0, 0);
    #pragma unroll
    for (int ks = 0; ks < 8; ++ks)
        bcur[ks] = *(const bf16x8*)(brow + ks * 32 + rg * 8);
    __syncthreads();

    constexpr int NS = CAT / 256;   // 50
    #pragma unroll 2
    for (int s = 0; s < NS; ++s) {
        const int cur = s & 1;
        const int kn  = (s + 1) * 256;
        if (s + 1 < NS) {
            stageA(cur ^ 1, kn);
            #pragma unroll
            for (int ks = 0; ks < 8; ++ks)
                bnxt[ks] = *(const bf16x8*)(brow + kn + ks * 32 + rg * 8);
        }
        #pragma unroll
        for (int ks = 0; ks < 8; ++ks) {
            bf16x8 a = *(const bf16x8*)&A[cur][rt * 16 + cl][ks * 32 + rg * 8];
            acc = __builtin_amdgcn_mfma_f32_16x16x32_bf16(a, bcur[ks], acc, 0, 0, 0);
        }
        __syncthreads();
        #pragma unroll
        for (int ks = 0; ks < 8; ++ks) bcur[ks] = bnxt[ks];
    }

    // epilogue: h = relu(acc + b1[col]); p-partial = h*W2[col]; reduce the
    // 16 col-lanes, then sum the 2 col-tiles via LDS; write p_q.
    const float b1c = b1[col];
    const float w2c = W2[col];

    #pragma unroll
    for (int r = 0; r < 4; ++r) {
        float h = fmaxf(acc[r] + b1c, 0.f);
        float p = h * w2c;
        p += __shfl_xor(p, 1, 64);
        p += __shfl_xor(p, 2, 64);
        p += __shfl_xor(p, 4, 64);
        p += __shfl_xor(p, 8, 64);
        if (cl == 0) red[w][rg * 4 + r] = p;
    }
    __syncthreads();
    if (t < 32) {
        int rt2 = t >> 4, lr = t & 15;
        float p = red[rt2][lr] + red[2 + rt2][lr];   // ct=0 wave + ct=1 wave
        pq[(size_t)q * bstride + b0 + row0 + t] = p;
    }
}

// ---------------------------------------------------------------------------
// combine: out = sigmoid(relu(p0+p1+p2+p3 + b2))   (fixed-order, determinist)
// ---------------------------------------------------------------------------
__global__ __launch_bounds__(256) void combine_sig(
    const float* __restrict__ pq, const float* __restrict__ b2,
    float* __restrict__ out, int bstride, int n)
{
    int t = blockIdx.x * 256 + threadIdx.x;
    if (t < n) {
        float o = pq[t] + pq[(size_t)bstride + t] + pq[2 * (size_t)bstride + t]
                + pq[3 * (size_t)bstride + t] + b2[0];
        o = fmaxf(o, 0.f);
        out[t] = 1.f / (1.f + expf(-o));
    }
}

// ---------------------------------------------------------------------------
extern "C" void kernel_launch(void* const* d_in, const int* in_sizes, int n_in,
                              void* d_out, int out_size, void* d_ws, size_t ws_size,
                              hipStream_t stream)
{
    const int*   user_idxs = (const int*)d_in[0];
    const int*   item_idxs = (const int*)d_in[1];
    const int*   user_nbt  = (const int*)d_in[2];
    const int*   item_nbt  = (const int*)d_in[3];
    const float* user_scr  = (const float*)d_in[4];
    const float* item_scr  = (const float*)d_in[5];
    const float* user_emb  = (const float*)d_in[6];
    const float* item_emb  = (const float*)d_in[7];
    const float* W1        = (const float*)d_in[8];
    const float* b1        = (const float*)d_in[9];
    const float* W2        = (const float*)d_in[10];
    const float* b2        = (const float*)d_in[11];
    float*       out       = (float*)d_out;

    const int B = in_sizes[0];      // 8192

    // ws layout: [w1t][us_bf][is_bf][ue_bf][ie_bf][pq: 4*B f32][xb]
    char* p = (char*)d_ws;
    unsigned short* w1t   = (unsigned short*)p;  p += (size_t)HID * CAT * 2;
    unsigned short* us_bf = (unsigned short*)p;  p += (size_t)in_sizes[4] * 2;
    unsigned short* is_bf = (unsigned short*)p;  p += (size_t)in_sizes[5] * 2;
    unsigned short* ue_bf = (unsigned short*)p;  p += (size_t)in_sizes[6] * 2;
    unsigned short* ie_bf = (unsigned short*)p;  p += (size_t)in_sizes[7] * 2;
    float*          pqb   = (float*)p;           p += (size_t)4 * B * sizeof(float);
    unsigned short* xb    = (unsigned short*)p;
    const size_t fixed = (size_t)(p - (char*)d_ws);

    const size_t row_bytes = (size_t)CAT * sizeof(unsigned short);
    long max_rows = (long)((ws_size - fixed) / row_bytes);
    int chunk = (int)((max_rows / 32) * 32);
    if (chunk > CHUNK) chunk = CHUNK;       // L3-residency cap
    if (chunk > B) chunk = B;
    if (chunk < 32) chunk = 32;

    prep_w1t<<<CAT / 64, 256, 0, stream>>>(W1, w1t);
    cvt4<<<dim3(512, 4), 256, 0, stream>>>(
        user_scr, us_bf, in_sizes[4] / 4,
        item_scr, is_bf, in_sizes[5] / 4,
        user_emb, ue_bf, in_sizes[6] / 4,
        item_emb, ie_bf, in_sizes[7] / 4);

    for (int b0 = 0; b0 < B; b0 += chunk) {
        int rows = (B - b0 < chunk) ? (B - b0) : chunk;
        einsum_mfma<<<dim3(rows, 2), 256, 0, stream>>>(
            user_idxs, item_idxs, user_nbt, item_nbt,
            us_bf, is_bf, ue_bf, ie_bf, xb, b0);
        mlp_partial<<<dim3(rows / 32, 4), 256, 0, stream>>>(
            xb, w1t, b1, W2, pqb, b0, B);
    }
    combine_sig<<<(B + 255) / 256, 256, 0, stream>>>(pqb, b2, out, B, B);
}

// Round 11
// 436.339 us; speedup vs baseline: 1.0304x; 1.0304x over previous
//
#include <hip/hip_runtime.h>
#include <hip/hip_bf16.h>
#include <math.h>

constexpr int KN  = 100;            // K (multi_factor * top_k)
constexpr int DE  = 64;             // embedding dim
constexpr int CAT = 2 * KN * DE;    // 12800
constexpr int HID = 128;
constexpr int CHUNK = 4096;         // einsum pipeline chunk (tables L3-resident)
constexpr int KSPLIT = 4;
constexpr int KSEG = CAT / KSPLIT;  // 3200

typedef __bf16          bf16x8   __attribute__((ext_vector_type(8)));
typedef float           f32x4    __attribute__((ext_vector_type(4)));
typedef unsigned short  ushort8v __attribute__((ext_vector_type(8)));
typedef unsigned short  ushort4v __attribute__((ext_vector_type(4)));

static __device__ __forceinline__ unsigned short f2bf(float f) {
    __hip_bfloat16 h = __float2bfloat16(f);
    return *reinterpret_cast<unsigned short*>(&h);
}

static __device__ __forceinline__ bf16x8 mk_frag(ushort4v lo, ushort4v hi) {
    union { ushort8v u; bf16x8 b; } c;
    c.u = (ushort8v){ lo[0], lo[1], lo[2], lo[3], hi[0], hi[1], hi[2], hi[3] };
    return c.b;
}

// ---------------------------------------------------------------------------
// prep: 4 fp32->bf16 table conversions in one launch
// ---------------------------------------------------------------------------
__global__ __launch_bounds__(256) void cvt4(
    const float* __restrict__ a0, unsigned short* __restrict__ o0, int n0,
    const float* __restrict__ a1, unsigned short* __restrict__ o1, int n1,
    const float* __restrict__ a2, unsigned short* __restrict__ o2, int n2,
    const float* __restrict__ a3, unsigned short* __restrict__ o3, int n3)
{
    const float* in; unsigned short* out; int n4;
    switch (blockIdx.y) {
        case 0:  in = a0; out = o0; n4 = n0; break;
        case 1:  in = a1; out = o1; n4 = n1; break;
        case 2:  in = a2; out = o2; n4 = n2; break;
        default: in = a3; out = o3; n4 = n3; break;
    }
    for (int i = blockIdx.x * 256 + threadIdx.x; i < n4; i += gridDim.x * 256) {
        float4 v = ((const float4*)in)[i];
        ushort4v o = { f2bf(v.x), f2bf(v.y), f2bf(v.z), f2bf(v.w) };
        ((ushort4v*)out)[i] = o;
    }
}

// ---------------------------------------------------------------------------
// prep: w1t[n][k] = bf16(W1[k][n])
// ---------------------------------------------------------------------------
__global__ __launch_bounds__(256) void prep_w1t(
    const float* __restrict__ W1, unsigned short* __restrict__ w1t)
{
    __shared__ unsigned short T[HID][72];
    const int t  = threadIdx.x;
    const int k0 = blockIdx.x * 64;

    for (int idx = t; idx < 64 * HID; idx += 256) {
        int kk = idx >> 7, n = idx & 127;
        T[n][kk] = f2bf(W1[(size_t)(k0 + kk) * HID + n]);
    }
    __syncthreads();
    for (int idx = t; idx < HID * 16; idx += 256) {
        int n = idx >> 4, c4 = idx & 15;
        *(ushort4v*)&w1t[(size_t)n * CAT + k0 + c4 * 4] =
            *(const ushort4v*)&T[n][c4 * 4];
    }
}

// ---------------------------------------------------------------------------
// Kernel 1 (unchanged — proven ~62us/chunk with L3-resident tables)
// ---------------------------------------------------------------------------
__global__ __launch_bounds__(256) void einsum_mfma(
    const int* __restrict__ u_idx, const int* __restrict__ i_idx,
    const int* __restrict__ u_nbt, const int* __restrict__ i_nbt,
    const unsigned short* __restrict__ u_scr, const unsigned short* __restrict__ i_scr,
    const unsigned short* __restrict__ u_emb, const unsigned short* __restrict__ i_emb,
    unsigned short* __restrict__ xb, int b0)
{
    __shared__ __align__(16) unsigned short ET[64][136];
    __shared__ int nb[KN];

    const int t    = threadIdx.x;
    const int side = blockIdx.y;
    const int b    = b0 + blockIdx.x;

    const int*            idxs = side ? i_idx : u_idx;
    const int*            nbt  = side ? i_nbt : u_nbt;
    const unsigned short* scr  = side ? i_scr : u_scr;
    const unsigned short* emb  = side ? i_emb : u_emb;

    const ushort4v z4 = {0, 0, 0, 0};

    const int center = idxs[b];
    if (t < KN) nb[t] = nbt[(size_t)center * KN + t];

    for (int idx = t; idx < 64 * 7; idx += 256) {
        int r = idx / 7, c = idx - r * 7;
        *(ushort4v*)&ET[r][100 + c * 4] = z4;
    }
    __syncthreads();                           // nb ready

    for (int idx = t; idx < 25 * 16; idx += 256) {
        int d4 = idx / 25, j0 = idx - d4 * 25;
        ushort4v v0 = *(const ushort4v*)(emb + (size_t)nb[j0 * 4 + 0] * DE + d4 * 4);
        ushort4v v1 = *(const ushort4v*)(emb + (size_t)nb[j0 * 4 + 1] * DE + d4 * 4);
        ushort4v v2 = *(const ushort4v*)(emb + (size_t)nb[j0 * 4 + 2] * DE + d4 * 4);
        ushort4v v3 = *(const ushort4v*)(emb + (size_t)nb[j0 * 4 + 3] * DE + d4 * 4);
        ushort4v o0 = { v0[0], v1[0], v2[0], v3[0] };
        ushort4v o1 = { v0[1], v1[1], v2[1], v3[1] };
        ushort4v o2 = { v0[2], v1[2], v2[2], v3[2] };
        ushort4v o3 = { v0[3], v1[3], v2[3], v3[3] };
        *(ushort4v*)&ET[d4 * 4 + 0][j0 * 4] = o0;
        *(ushort4v*)&ET[d4 * 4 + 1][j0 * 4] = o1;
        *(ushort4v*)&ET[d4 * 4 + 2][j0 * 4] = o2;
        *(ushort4v*)&ET[d4 * 4 + 3][j0 * 4] = o3;
    }
    __syncthreads();

    const int w  = t >> 6;
    const int l  = t & 63;
    const int cl = l & 15;
    const int rg = l >> 4;

    const unsigned short* srow[7];
    #pragma unroll
    for (int mt = 0; mt < 7; ++mt) {
        int kr = mt * 16 + cl;
        if (kr > KN - 1) kr = KN - 1;
        srow[mt] = scr + (size_t)nb[kr] * KN;
    }

    f32x4 acc[7];
    #pragma unroll
    for (int m = 0; m < 7; ++m) acc[m] = (f32x4){0.f, 0.f, 0.f, 0.f};

    #pragma unroll
    for (int ks = 0; ks < 4; ++ks) {
        const int k0 = ks * 32 + rg * 8;
        bf16x8 bfrag = *(const bf16x8*)&ET[w * 16 + cl][k0];
        #pragma unroll
        for (int mt = 0; mt < 7; ++mt) {
            ushort4v lo, hi;
            if (ks < 3) {
                lo = *(const ushort4v*)(srow[mt] + k0);
                hi = *(const ushort4v*)(srow[mt] + k0 + 4);
            } else if (rg == 0) {
                lo = *(const ushort4v*)(srow[mt] + 96);
                hi = z4;
            } else {
                lo = z4; hi = z4;
            }
            bf16x8 afrag = mk_frag(lo, hi);
            acc[mt] = __builtin_amdgcn_mfma_f32_16x16x32_bf16(afrag, bfrag, acc[mt], 0, 0, 0);
        }
    }
    __syncthreads();

    unsigned short* X = &ET[0][0];
    #pragma unroll
    for (int mt = 0; mt < 7; ++mt) {
        #pragma unroll
        for (int rr = 0; rr < 4; ++rr) {
            int k = mt * 16 + rg * 4 + rr;
            if (k < KN) X[k * 72 + w * 16 + cl] = f2bf(acc[mt][rr]);
        }
    }
    __syncthreads();

    unsigned short* xr = xb + (size_t)blockIdx.x * CAT + side * (KN * DE);
    for (int idx = t; idx < KN * 8; idx += 256) {
        int r = idx >> 3, c8 = idx & 7;
        *(ushort8v*)&xr[r * DE + c8 * 8] = *(const ushort8v*)&X[r * 72 + c8 * 8];
    }
}

// ---------------------------------------------------------------------------
// Kernel 2 (v10b): K-split MLP h-partials.  Grid (B/32, 4).  Block = 32 rows
// x 128 cols x K-seg 3200.  256 threads = 4 waves: wave w -> row-tile w&1,
// col-half (w>>1)*64 (4 16-col frags).  A LDS-dbuf (BK=128); B direct
// global->reg from L2-resident w1t.  h-partials are LINEAR in K -> store
// f32 hp[q][row][128]; relu/W2/sigmoid applied in combine (exact).
// xb read exactly once.  1024 blocks = 4/CU.
// ---------------------------------------------------------------------------
__global__ __launch_bounds__(256) void mlp_kpart(
    const unsigned short* __restrict__ xb, const unsigned short* __restrict__ w1t,
    float* __restrict__ hp, int Btot)
{
    __shared__ unsigned short A[2][32][136];   // 17.4 KB

    const int t  = threadIdx.x;
    const int w  = t >> 6;
    const int l  = t & 63;
    const int cl = l & 15;
    const int rg = l >> 4;
    const int rt = w & 1;           // row-tile (16 rows)
    const int ch = w >> 1;          // col-half (64 cols)
    const int row0  = blockIdx.x * 32;
    const int q     = blockIdx.y;
    const int kbase = q * KSEG;

    // per-lane B row bases (4 col-frags x 16 cols)
    const unsigned short* brow[4];
    #pragma unroll
    for (int nc = 0; nc < 4; ++nc)
        brow[nc] = w1t + (size_t)(ch * 64 + nc * 16 + cl) * CAT + kbase;

    auto stageA = [&](int buf, int kb) {
        #pragma unroll
        for (int i = 0; i < 2; ++i) {
            int c = t + i * 256;
            int r = c >> 4, c16 = c & 15;
            *(ushort8v*)&A[buf][r][c16 * 8] =
                *(const ushort8v*)&xb[(size_t)(row0 + r) * CAT + kbase + kb + c16 * 8];
        }
    };

    f32x4 acc[4];
    #pragma unroll
    for (int nc = 0; nc < 4; ++nc) acc[nc] = (f32x4){0.f, 0.f, 0.f, 0.f};

    stageA(0, 0);
    __syncthreads();

    constexpr int NS = KSEG / 128;  // 25
    for (int s = 0; s < NS; ++s) {
        const int cur = s & 1;
        if (s + 1 < NS) stageA(cur ^ 1, (s + 1) * 128);
        #pragma unroll
        for (int ks = 0; ks < 4; ++ks) {
            const int kc = s * 128 + ks * 32 + rg * 8;
            bf16x8 a = *(const bf16x8*)&A[cur][rt * 16 + cl][ks * 32 + rg * 8];
            #pragma unroll
            for (int nc = 0; nc < 4; ++nc) {
                bf16x8 bv = *(const bf16x8*)(brow[nc] + kc);
                acc[nc] = __builtin_amdgcn_mfma_f32_16x16x32_bf16(a, bv, acc[nc], 0, 0, 0);
            }
        }
        __syncthreads();
    }

    // store h-partials: row = row0 + rt*16 + rg*4 + r; col = ch*64 + nc*16 + cl
    #pragma unroll
    for (int nc = 0; nc < 4; ++nc) {
        #pragma unroll
        for (int r = 0; r < 4; ++r) {
            size_t row = (size_t)row0 + rt * 16 + rg * 4 + r;
            hp[((size_t)q * Btot + row) * HID + ch * 64 + nc * 16 + cl] = acc[nc][r];
        }
    }
}

// ---------------------------------------------------------------------------
// combine: h = relu(sum_q hp + b1); o = relu(h.W2 + b2); out = sigmoid(o).
// 256 threads = 4 waves; waves 0-1 -> row A (cols 0-63 / 64-127), 2-3 -> row B.
// ---------------------------------------------------------------------------
__global__ __launch_bounds__(256) void combine_sig(
    const float* __restrict__ hp, const float* __restrict__ b1,
    const float* __restrict__ W2, const float* __restrict__ b2,
    float* __restrict__ out, int Btot)
{
    __shared__ float red[4];
    const int t   = threadIdx.x;
    const int w   = t >> 6;
    const int l   = t & 63;
    const int rsel = w >> 1;                  // 0/1: which row of this block
    const int col  = (w & 1) * 64 + l;
    const size_t row = (size_t)blockIdx.x * 2 + rsel;

    const float* hpr = hp + row * HID + col;
    float v = hpr[0] + hpr[(size_t)Btot * HID] + hpr[2 * (size_t)Btot * HID]
            + hpr[3 * (size_t)Btot * HID] + b1[col];
    float p = fmaxf(v, 0.f) * W2[col];
    p += __shfl_xor(p, 1,  64);
    p += __shfl_xor(p, 2,  64);
    p += __shfl_xor(p, 4,  64);
    p += __shfl_xor(p, 8,  64);
    p += __shfl_xor(p, 16, 64);
    p += __shfl_xor(p, 32, 64);
    if (l == 0) red[w] = p;
    __syncthreads();
    if (t < 2) {
        float o = red[2 * t] + red[2 * t + 1] + b2[0];
        o = fmaxf(o, 0.f);
        out[blockIdx.x * 2 + t] = 1.f / (1.f + expf(-o));
    }
}

// ---------------------------------------------------------------------------
extern "C" void kernel_launch(void* const* d_in, const int* in_sizes, int n_in,
                              void* d_out, int out_size, void* d_ws, size_t ws_size,
                              hipStream_t stream)
{
    const int*   user_idxs = (const int*)d_in[0];
    const int*   item_idxs = (const int*)d_in[1];
    const int*   user_nbt  = (const int*)d_in[2];
    const int*   item_nbt  = (const int*)d_in[3];
    const float* user_scr  = (const float*)d_in[4];
    const float* item_scr  = (const float*)d_in[5];
    const float* user_emb  = (const float*)d_in[6];
    const float* item_emb  = (const float*)d_in[7];
    const float* W1        = (const float*)d_in[8];
    const float* b1        = (const float*)d_in[9];
    const float* W2        = (const float*)d_in[10];
    const float* b2        = (const float*)d_in[11];
    float*       out       = (float*)d_out;

    const int B = in_sizes[0];      // 8192

    // ws layout: [w1t][us_bf][is_bf][ue_bf][ie_bf][xb]  (r6-proven footprint:
    // 52.7 MB fixed + 210 MB xb).  hp (16.8 MB) ALIASES the us_bf region
    // (20 MB): tables are dead after the last einsum dispatch, and stream
    // order guarantees einsum completes before mlp_kpart writes hp.  Every
    // graph replay re-runs cvt4 before einsum, so the aliasing is
    // deterministic across calls.
    char* p = (char*)d_ws;
    unsigned short* w1t   = (unsigned short*)p;  p += (size_t)HID * CAT * 2;
    unsigned short* us_bf = (unsigned short*)p;  p += (size_t)in_sizes[4] * 2;
    unsigned short* is_bf = (unsigned short*)p;  p += (size_t)in_sizes[5] * 2;
    unsigned short* ue_bf = (unsigned short*)p;  p += (size_t)in_sizes[6] * 2;
    unsigned short* ie_bf = (unsigned short*)p;  p += (size_t)in_sizes[7] * 2;
    unsigned short* xb    = (unsigned short*)p;
    float*          hpb   = (float*)us_bf;       // alias (16.8 MB <= 20 MB)

    prep_w1t<<<CAT / 64, 256, 0, stream>>>(W1, w1t);
    cvt4<<<dim3(512, 4), 256, 0, stream>>>(
        user_scr, us_bf, in_sizes[4] / 4,
        item_scr, is_bf, in_sizes[5] / 4,
        user_emb, ue_bf, in_sizes[6] / 4,
        item_emb, ie_bf, in_sizes[7] / 4);

    // einsum chunked (tables L3-resident); xb laid out for the FULL batch
    for (int b0 = 0; b0 < B; b0 += CHUNK) {
        int rows = (B - b0 < CHUNK) ? (B - b0) : CHUNK;
        einsum_mfma<<<dim3(rows, 2), 256, 0, stream>>>(
            user_idxs, item_idxs, user_nbt, item_nbt,
            us_bf, is_bf, ue_bf, ie_bf, xb + (size_t)b0 * CAT, b0);
    }
    // MLP once over the full batch: K-split partials + combine
    mlp_kpart<<<dim3(B / 32, KSPLIT), 256, 0, stream>>>(xb, w1t, hpb, B);
    combine_sig<<<B / 2, 256, 0, stream>>>(hpb, b1, W2, b2, out, B);
}

// Round 12
// 378.019 us; speedup vs baseline: 1.1893x; 1.1543x over previous
//
#include <hip/hip_runtime.h>
#include <hip/hip_bf16.h>
#include <math.h>

constexpr int KN  = 100;            // K (multi_factor * top_k)
constexpr int DE  = 64;             // embedding dim
constexpr int CAT = 2 * KN * DE;    // 12800
constexpr int HID = 128;
constexpr int CHUNK = 4096;         // einsum pipeline chunk (tables L3-resident)

typedef __bf16          bf16x8   __attribute__((ext_vector_type(8)));
typedef float           f32x4    __attribute__((ext_vector_type(4)));
typedef unsigned short  ushort8v __attribute__((ext_vector_type(8)));
typedef unsigned short  ushort4v __attribute__((ext_vector_type(4)));

static __device__ __forceinline__ unsigned short f2bf(float f) {
    __hip_bfloat16 h = __float2bfloat16(f);
    return *reinterpret_cast<unsigned short*>(&h);
}

static __device__ __forceinline__ bf16x8 mk_frag(ushort4v lo, ushort4v hi) {
    union { ushort8v u; bf16x8 b; } c;
    c.u = (ushort8v){ lo[0], lo[1], lo[2], lo[3], hi[0], hi[1], hi[2], hi[3] };
    return c.b;
}

// ---------------------------------------------------------------------------
// prep: 4 fp32->bf16 table conversions in one launch
// ---------------------------------------------------------------------------
__global__ __launch_bounds__(256) void cvt4(
    const float* __restrict__ a0, unsigned short* __restrict__ o0, int n0,
    const float* __restrict__ a1, unsigned short* __restrict__ o1, int n1,
    const float* __restrict__ a2, unsigned short* __restrict__ o2, int n2,
    const float* __restrict__ a3, unsigned short* __restrict__ o3, int n3)
{
    const float* in; unsigned short* out; int n4;
    switch (blockIdx.y) {
        case 0:  in = a0; out = o0; n4 = n0; break;
        case 1:  in = a1; out = o1; n4 = n1; break;
        case 2:  in = a2; out = o2; n4 = n2; break;
        default: in = a3; out = o3; n4 = n3; break;
    }
    for (int i = blockIdx.x * 256 + threadIdx.x; i < n4; i += gridDim.x * 256) {
        float4 v = ((const float4*)in)[i];
        ushort4v o = { f2bf(v.x), f2bf(v.y), f2bf(v.z), f2bf(v.w) };
        ((ushort4v*)out)[i] = o;
    }
}

// ---------------------------------------------------------------------------
// prep: w1t[n][k] = bf16(W1[k][n])
// ---------------------------------------------------------------------------
__global__ __launch_bounds__(256) void prep_w1t(
    const float* __restrict__ W1, unsigned short* __restrict__ w1t)
{
    __shared__ unsigned short T[HID][72];
    const int t  = threadIdx.x;
    const int k0 = blockIdx.x * 64;

    for (int idx = t; idx < 64 * HID; idx += 256) {
        int kk = idx >> 7, n = idx & 127;
        T[n][kk] = f2bf(W1[(size_t)(k0 + kk) * HID + n]);
    }
    __syncthreads();
    for (int idx = t; idx < HID * 16; idx += 256) {
        int n = idx >> 4, c4 = idx & 15;
        *(ushort4v*)&w1t[(size_t)n * CAT + k0 + c4 * 4] =
            *(const ushort4v*)&T[n][c4 * 4];
    }
}

// ---------------------------------------------------------------------------
// Kernel 1 (unchanged — proven ~62us/chunk with L3-resident tables)
// ---------------------------------------------------------------------------
__global__ __launch_bounds__(256) void einsum_mfma(
    const int* __restrict__ u_idx, const int* __restrict__ i_idx,
    const int* __restrict__ u_nbt, const int* __restrict__ i_nbt,
    const unsigned short* __restrict__ u_scr, const unsigned short* __restrict__ i_scr,
    const unsigned short* __restrict__ u_emb, const unsigned short* __restrict__ i_emb,
    unsigned short* __restrict__ xb, int b0)
{
    __shared__ __align__(16) unsigned short ET[64][136];
    __shared__ int nb[KN];

    const int t    = threadIdx.x;
    const int side = blockIdx.y;
    const int b    = b0 + blockIdx.x;

    const int*            idxs = side ? i_idx : u_idx;
    const int*            nbt  = side ? i_nbt : u_nbt;
    const unsigned short* scr  = side ? i_scr : u_scr;
    const unsigned short* emb  = side ? i_emb : u_emb;

    const ushort4v z4 = {0, 0, 0, 0};

    const int center = idxs[b];
    if (t < KN) nb[t] = nbt[(size_t)center * KN + t];

    for (int idx = t; idx < 64 * 7; idx += 256) {
        int r = idx / 7, c = idx - r * 7;
        *(ushort4v*)&ET[r][100 + c * 4] = z4;
    }
    __syncthreads();                           // nb ready

    for (int idx = t; idx < 25 * 16; idx += 256) {
        int d4 = idx / 25, j0 = idx - d4 * 25;
        ushort4v v0 = *(const ushort4v*)(emb + (size_t)nb[j0 * 4 + 0] * DE + d4 * 4);
        ushort4v v1 = *(const ushort4v*)(emb + (size_t)nb[j0 * 4 + 1] * DE + d4 * 4);
        ushort4v v2 = *(const ushort4v*)(emb + (size_t)nb[j0 * 4 + 2] * DE + d4 * 4);
        ushort4v v3 = *(const ushort4v*)(emb + (size_t)nb[j0 * 4 + 3] * DE + d4 * 4);
        ushort4v o0 = { v0[0], v1[0], v2[0], v3[0] };
        ushort4v o1 = { v0[1], v1[1], v2[1], v3[1] };
        ushort4v o2 = { v0[2], v1[2], v2[2], v3[2] };
        ushort4v o3 = { v0[3], v1[3], v2[3], v3[3] };
        *(ushort4v*)&ET[d4 * 4 + 0][j0 * 4] = o0;
        *(ushort4v*)&ET[d4 * 4 + 1][j0 * 4] = o1;
        *(ushort4v*)&ET[d4 * 4 + 2][j0 * 4] = o2;
        *(ushort4v*)&ET[d4 * 4 + 3][j0 * 4] = o3;
    }
    __syncthreads();

    const int w  = t >> 6;
    const int l  = t & 63;
    const int cl = l & 15;
    const int rg = l >> 4;

    const unsigned short* srow[7];
    #pragma unroll
    for (int mt = 0; mt < 7; ++mt) {
        int kr = mt * 16 + cl;
        if (kr > KN - 1) kr = KN - 1;
        srow[mt] = scr + (size_t)nb[kr] * KN;
    }

    f32x4 acc[7];
    #pragma unroll
    for (int m = 0; m < 7; ++m) acc[m] = (f32x4){0.f, 0.f, 0.f, 0.f};

    #pragma unroll
    for (int ks = 0; ks < 4; ++ks) {
        const int k0 = ks * 32 + rg * 8;
        bf16x8 bfrag = *(const bf16x8*)&ET[w * 16 + cl][k0];
        #pragma unroll
        for (int mt = 0; mt < 7; ++mt) {
            ushort4v lo, hi;
            if (ks < 3) {
                lo = *(const ushort4v*)(srow[mt] + k0);
                hi = *(const ushort4v*)(srow[mt] + k0 + 4);
            } else if (rg == 0) {
                lo = *(const ushort4v*)(srow[mt] + 96);
                hi = z4;
            } else {
                lo = z4; hi = z4;
            }
            bf16x8 afrag = mk_frag(lo, hi);
            acc[mt] = __builtin_amdgcn_mfma_f32_16x16x32_bf16(afrag, bfrag, acc[mt], 0, 0, 0);
        }
    }
    __syncthreads();

    unsigned short* X = &ET[0][0];
    #pragma unroll
    for (int mt = 0; mt < 7; ++mt) {
        #pragma unroll
        for (int rr = 0; rr < 4; ++rr) {
            int k = mt * 16 + rg * 4 + rr;
            if (k < KN) X[k * 72 + w * 16 + cl] = f2bf(acc[mt][rr]);
        }
    }
    __syncthreads();

    unsigned short* xr = xb + (size_t)blockIdx.x * CAT + side * (KN * DE);
    for (int idx = t; idx < KN * 8; idx += 256) {
        int r = idx >> 3, c8 = idx & 7;
        *(ushort8v*)&xr[r * DE + c8 * 8] = *(const ushort8v*)&X[r * 72 + c8 * 8];
    }
}

// ---------------------------------------------------------------------------
// Kernel 2 (v12): the r2-proven MLP structure (BM=32, full 128 cols, 4 waves,
// coalesced LDS staging of A and Bt) + DOUBLE BUFFERING: stage K-step s+1
// before computing step s, one barrier per step.  Full batch, grid 256 =
// 1 block/CU.  Fused bias/relu/W2/sigmoid epilogue.
// ---------------------------------------------------------------------------
__global__ __launch_bounds__(256) void mlp_fused(
    const unsigned short* __restrict__ xb, const unsigned short* __restrict__ w1t,
    const float* __restrict__ b1, const float* __restrict__ W2,
    const float* __restrict__ b2, float* __restrict__ out)
{
    __shared__ unsigned short A[2][32][136];    // 17.4 KB
    __shared__ unsigned short Bt[2][HID][136];  // 69.6 KB
    __shared__ float red[4][32];

    const int t    = threadIdx.x;
    const int w    = t >> 6;
    const int l    = t & 63;
    const int cl   = l & 15;
    const int rgrp = l >> 4;
    const int row0 = blockIdx.x * 32;

    auto stage = [&](int buf, int kb) {
        #pragma unroll
        for (int i = 0; i < 2; ++i) {
            int c = t + i * 256;
            int r = c >> 4, c16 = c & 15;
            *(ushort8v*)&A[buf][r][c16 * 8] =
                *(const ushort8v*)&xb[(size_t)(row0 + r) * CAT + kb + c16 * 8];
        }
        #pragma unroll
        for (int i = 0; i < 8; ++i) {
            int c = t + i * 256;
            int n = c >> 4, c16 = c & 15;
            *(ushort8v*)&Bt[buf][n][c16 * 8] =
                *(const ushort8v*)&w1t[(size_t)n * CAT + kb + c16 * 8];
        }
    };

    f32x4 acc[2][2];
    #pragma unroll
    for (int i = 0; i < 2; ++i)
        #pragma unroll
        for (int j = 0; j < 2; ++j)
            acc[i][j] = (f32x4){0.f, 0.f, 0.f, 0.f};

    stage(0, 0);
    __syncthreads();

    constexpr int NS = CAT / 128;   // 100
    for (int s = 0; s < NS; ++s) {
        const int cur = s & 1;
        if (s + 1 < NS) stage(cur ^ 1, (s + 1) * 128);   // issue loads FIRST
        #pragma unroll
        for (int ks = 0; ks < 4; ++ks) {
            const int kcol = ks * 32 + rgrp * 8;
            bf16x8 a0 = *(const bf16x8*)&A[cur][cl][kcol];
            bf16x8 a1 = *(const bf16x8*)&A[cur][16 + cl][kcol];
            bf16x8 v0 = *(const bf16x8*)&Bt[cur][w * 32 + cl][kcol];
            bf16x8 v1 = *(const bf16x8*)&Bt[cur][w * 32 + 16 + cl][kcol];
            acc[0][0] = __builtin_amdgcn_mfma_f32_16x16x32_bf16(a0, v0, acc[0][0], 0, 0, 0);
            acc[0][1] = __builtin_amdgcn_mfma_f32_16x16x32_bf16(a0, v1, acc[0][1], 0, 0, 0);
            acc[1][0] = __builtin_amdgcn_mfma_f32_16x16x32_bf16(a1, v0, acc[1][0], 0, 0, 0);
            acc[1][1] = __builtin_amdgcn_mfma_f32_16x16x32_bf16(a1, v1, acc[1][1], 0, 0, 0);
        }
        __syncthreads();            // stage(s+1) done AND A/Bt[cur] reads done
    }

    const float b1c0 = b1[w * 32 + cl];
    const float b1c1 = b1[w * 32 + 16 + cl];
    const float w2c0 = W2[w * 32 + cl];
    const float w2c1 = W2[w * 32 + 16 + cl];

    #pragma unroll
    for (int mt = 0; mt < 2; ++mt) {
        #pragma unroll
        for (int r = 0; r < 4; ++r) {
            float h0 = fmaxf(acc[mt][0][r] + b1c0, 0.f);
            float h1 = fmaxf(acc[mt][1][r] + b1c1, 0.f);
            float p  = fmaf(h0, w2c0, h1 * w2c1);
            p += __shfl_xor(p, 1, 64);
            p += __shfl_xor(p, 2, 64);
            p += __shfl_xor(p, 4, 64);
            p += __shfl_xor(p, 8, 64);
            if (cl == 0) red[w][mt * 16 + rgrp * 4 + r] = p;
        }
    }
    __syncthreads();
    if (t < 32) {
        float o = red[0][t] + red[1][t] + red[2][t] + red[3][t] + b2[0];
        o = fmaxf(o, 0.f);
        out[row0 + t] = 1.f / (1.f + expf(-o));
    }
}

// ---------------------------------------------------------------------------
extern "C" void kernel_launch(void* const* d_in, const int* in_sizes, int n_in,
                              void* d_out, int out_size, void* d_ws, size_t ws_size,
                              hipStream_t stream)
{
    const int*   user_idxs = (const int*)d_in[0];
    const int*   item_idxs = (const int*)d_in[1];
    const int*   user_nbt  = (const int*)d_in[2];
    const int*   item_nbt  = (const int*)d_in[3];
    const float* user_scr  = (const float*)d_in[4];
    const float* item_scr  = (const float*)d_in[5];
    const float* user_emb  = (const float*)d_in[6];
    const float* item_emb  = (const float*)d_in[7];
    const float* W1        = (const float*)d_in[8];
    const float* b1        = (const float*)d_in[9];
    const float* W2        = (const float*)d_in[10];
    const float* b2        = (const float*)d_in[11];
    float*       out       = (float*)d_out;

    const int B = in_sizes[0];      // 8192

    // ws layout (r6-proven footprint: 52.7 MB fixed + 210 MB xb)
    char* p = (char*)d_ws;
    unsigned short* w1t   = (unsigned short*)p;  p += (size_t)HID * CAT * 2;
    unsigned short* us_bf = (unsigned short*)p;  p += (size_t)in_sizes[4] * 2;
    unsigned short* is_bf = (unsigned short*)p;  p += (size_t)in_sizes[5] * 2;
    unsigned short* ue_bf = (unsigned short*)p;  p += (size_t)in_sizes[6] * 2;
    unsigned short* ie_bf = (unsigned short*)p;  p += (size_t)in_sizes[7] * 2;
    unsigned short* xb    = (unsigned short*)p;

    prep_w1t<<<CAT / 64, 256, 0, stream>>>(W1, w1t);
    cvt4<<<dim3(512, 4), 256, 0, stream>>>(
        user_scr, us_bf, in_sizes[4] / 4,
        item_scr, is_bf, in_sizes[5] / 4,
        user_emb, ue_bf, in_sizes[6] / 4,
        item_emb, ie_bf, in_sizes[7] / 4);

    // einsum chunked (tables L3-resident during the gather phase)
    for (int b0 = 0; b0 < B; b0 += CHUNK) {
        int rows = (B - b0 < CHUNK) ? (B - b0) : CHUNK;
        einsum_mfma<<<dim3(rows, 2), 256, 0, stream>>>(
            user_idxs, item_idxs, user_nbt, item_nbt,
            us_bf, is_bf, ue_bf, ie_bf, xb + (size_t)b0 * CAT, b0);
    }
    // MLP once over the full batch: grid 256 = 1 block/CU, fused epilogue
    mlp_fused<<<B / 32, 256, 0, stream>>>(xb, w1t, b1, W2, b2, out);
}

// Round 13
// 304.000 us; speedup vs baseline: 1.4789x; 1.2435x over previous
//
#include <hip/hip_runtime.h>
#include <hip/hip_bf16.h>
#include <math.h>

constexpr int KN  = 100;            // K (multi_factor * top_k)
constexpr int DE  = 64;             // embedding dim
constexpr int CAT = 2 * KN * DE;    // 12800
constexpr int HID = 128;
constexpr int CHUNK = 4096;         // einsum pipeline chunk (tables L3-resident)
constexpr int KSPLIT = 4;
constexpr int KSEG = CAT / KSPLIT;  // 3200

typedef __bf16          bf16x8   __attribute__((ext_vector_type(8)));
typedef float           f32x4    __attribute__((ext_vector_type(4)));
typedef unsigned short  ushort8v __attribute__((ext_vector_type(8)));
typedef unsigned short  ushort4v __attribute__((ext_vector_type(4)));

static __device__ __forceinline__ unsigned short f2bf(float f) {
    __hip_bfloat16 h = __float2bfloat16(f);
    return *reinterpret_cast<unsigned short*>(&h);
}

static __device__ __forceinline__ bf16x8 mk_frag(ushort4v lo, ushort4v hi) {
    union { ushort8v u; bf16x8 b; } c;
    c.u = (ushort8v){ lo[0], lo[1], lo[2], lo[3], hi[0], hi[1], hi[2], hi[3] };
    return c.b;
}

// ---------------------------------------------------------------------------
// prep: 4 fp32->bf16 table conversions in one launch
// ---------------------------------------------------------------------------
__global__ __launch_bounds__(256) void cvt4(
    const float* __restrict__ a0, unsigned short* __restrict__ o0, int n0,
    const float* __restrict__ a1, unsigned short* __restrict__ o1, int n1,
    const float* __restrict__ a2, unsigned short* __restrict__ o2, int n2,
    const float* __restrict__ a3, unsigned short* __restrict__ o3, int n3)
{
    const float* in; unsigned short* out; int n4;
    switch (blockIdx.y) {
        case 0:  in = a0; out = o0; n4 = n0; break;
        case 1:  in = a1; out = o1; n4 = n1; break;
        case 2:  in = a2; out = o2; n4 = n2; break;
        default: in = a3; out = o3; n4 = n3; break;
    }
    for (int i = blockIdx.x * 256 + threadIdx.x; i < n4; i += gridDim.x * 256) {
        float4 v = ((const float4*)in)[i];
        ushort4v o = { f2bf(v.x), f2bf(v.y), f2bf(v.z), f2bf(v.w) };
        ((ushort4v*)out)[i] = o;
    }
}

// ---------------------------------------------------------------------------
// prep: w1t[n][k] = bf16(W1[k][n])
// ---------------------------------------------------------------------------
__global__ __launch_bounds__(256) void prep_w1t(
    const float* __restrict__ W1, unsigned short* __restrict__ w1t)
{
    __shared__ unsigned short T[HID][72];
    const int t  = threadIdx.x;
    const int k0 = blockIdx.x * 64;

    for (int idx = t; idx < 64 * HID; idx += 256) {
        int kk = idx >> 7, n = idx & 127;
        T[n][kk] = f2bf(W1[(size_t)(k0 + kk) * HID + n]);
    }
    __syncthreads();
    for (int idx = t; idx < HID * 16; idx += 256) {
        int n = idx >> 4, c4 = idx & 15;
        *(ushort4v*)&w1t[(size_t)n * CAT + k0 + c4 * 4] =
            *(const ushort4v*)&T[n][c4 * 4];
    }
}

// ---------------------------------------------------------------------------
// Kernel 1 (unchanged — proven ~62us/chunk with L3-resident tables)
// ---------------------------------------------------------------------------
__global__ __launch_bounds__(256) void einsum_mfma(
    const int* __restrict__ u_idx, const int* __restrict__ i_idx,
    const int* __restrict__ u_nbt, const int* __restrict__ i_nbt,
    const unsigned short* __restrict__ u_scr, const unsigned short* __restrict__ i_scr,
    const unsigned short* __restrict__ u_emb, const unsigned short* __restrict__ i_emb,
    unsigned short* __restrict__ xb, int b0)
{
    __shared__ __align__(16) unsigned short ET[64][136];
    __shared__ int nb[KN];

    const int t    = threadIdx.x;
    const int side = blockIdx.y;
    const int b    = b0 + blockIdx.x;

    const int*            idxs = side ? i_idx : u_idx;
    const int*            nbt  = side ? i_nbt : u_nbt;
    const unsigned short* scr  = side ? i_scr : u_scr;
    const unsigned short* emb  = side ? i_emb : u_emb;

    const ushort4v z4 = {0, 0, 0, 0};

    const int center = idxs[b];
    if (t < KN) nb[t] = nbt[(size_t)center * KN + t];

    for (int idx = t; idx < 64 * 7; idx += 256) {
        int r = idx / 7, c = idx - r * 7;
        *(ushort4v*)&ET[r][100 + c * 4] = z4;
    }
    __syncthreads();                           // nb ready

    for (int idx = t; idx < 25 * 16; idx += 256) {
        int d4 = idx / 25, j0 = idx - d4 * 25;
        ushort4v v0 = *(const ushort4v*)(emb + (size_t)nb[j0 * 4 + 0] * DE + d4 * 4);
        ushort4v v1 = *(const ushort4v*)(emb + (size_t)nb[j0 * 4 + 1] * DE + d4 * 4);
        ushort4v v2 = *(const ushort4v*)(emb + (size_t)nb[j0 * 4 + 2] * DE + d4 * 4);
        ushort4v v3 = *(const ushort4v*)(emb + (size_t)nb[j0 * 4 + 3] * DE + d4 * 4);
        ushort4v o0 = { v0[0], v1[0], v2[0], v3[0] };
        ushort4v o1 = { v0[1], v1[1], v2[1], v3[1] };
        ushort4v o2 = { v0[2], v1[2], v2[2], v3[2] };
        ushort4v o3 = { v0[3], v1[3], v2[3], v3[3] };
        *(ushort4v*)&ET[d4 * 4 + 0][j0 * 4] = o0;
        *(ushort4v*)&ET[d4 * 4 + 1][j0 * 4] = o1;
        *(ushort4v*)&ET[d4 * 4 + 2][j0 * 4] = o2;
        *(ushort4v*)&ET[d4 * 4 + 3][j0 * 4] = o3;
    }
    __syncthreads();

    const int w  = t >> 6;
    const int l  = t & 63;
    const int cl = l & 15;
    const int rg = l >> 4;

    const unsigned short* srow[7];
    #pragma unroll
    for (int mt = 0; mt < 7; ++mt) {
        int kr = mt * 16 + cl;
        if (kr > KN - 1) kr = KN - 1;
        srow[mt] = scr + (size_t)nb[kr] * KN;
    }

    f32x4 acc[7];
    #pragma unroll
    for (int m = 0; m < 7; ++m) acc[m] = (f32x4){0.f, 0.f, 0.f, 0.f};

    #pragma unroll
    for (int ks = 0; ks < 4; ++ks) {
        const int k0 = ks * 32 + rg * 8;
        bf16x8 bfrag = *(const bf16x8*)&ET[w * 16 + cl][k0];
        #pragma unroll
        for (int mt = 0; mt < 7; ++mt) {
            ushort4v lo, hi;
            if (ks < 3) {
                lo = *(const ushort4v*)(srow[mt] + k0);
                hi = *(const ushort4v*)(srow[mt] + k0 + 4);
            } else if (rg == 0) {
                lo = *(const ushort4v*)(srow[mt] + 96);
                hi = z4;
            } else {
                lo = z4; hi = z4;
            }
            bf16x8 afrag = mk_frag(lo, hi);
            acc[mt] = __builtin_amdgcn_mfma_f32_16x16x32_bf16(afrag, bfrag, acc[mt], 0, 0, 0);
        }
    }
    __syncthreads();

    unsigned short* X = &ET[0][0];
    #pragma unroll
    for (int mt = 0; mt < 7; ++mt) {
        #pragma unroll
        for (int rr = 0; rr < 4; ++rr) {
            int k = mt * 16 + rg * 4 + rr;
            if (k < KN) X[k * 72 + w * 16 + cl] = f2bf(acc[mt][rr]);
        }
    }
    __syncthreads();

    unsigned short* xr = xb + (size_t)blockIdx.x * CAT + side * (KN * DE);
    for (int idx = t; idx < KN * 8; idx += 256) {
        int r = idx >> 3, c8 = idx & 7;
        *(ushort8v*)&xr[r * DE + c8 * 8] = *(const ushort8v*)&X[r * 72 + c8 * 8];
    }
}

// ---------------------------------------------------------------------------
// Kernel 2 (v13): K-split MLP h-partials, occupancy-tuned.
// Grid (B/64, 4) = 512 blocks = 2 blocks/CU (LDS 55KB) -> two independent
// barrier domains per CU: one block's MFMA covers the other's staging drain.
// Block = 64 rows x 128 cols x K-seg 3200, BK=64 (50 steps), LDS dbuf for
// BOTH A and Bt (coalesced staging, r12-style).  BM=64 halves Bt re-fetch
// vs BM=32.  h-partials linear in K -> hp[q][row][128] f32; combine applies
// b1/relu/W2/b2/sigmoid exactly.
// ---------------------------------------------------------------------------
__global__ __launch_bounds__(256) void mlp_kpart(
    const unsigned short* __restrict__ xb, const unsigned short* __restrict__ w1t,
    float* __restrict__ hp, int Btot)
{
    __shared__ unsigned short A[2][64][72];    // 18.4 KB (+8 pad -> 2-way banks)
    __shared__ unsigned short Bt[2][HID][72];  // 36.9 KB

    const int t  = threadIdx.x;
    const int w  = t >> 6;
    const int l  = t & 63;
    const int cl = l & 15;
    const int rg = l >> 4;
    const int row0  = blockIdx.x * 64;
    const int q     = blockIdx.y;
    const int kbase = q * KSEG;

    auto stage = [&](int buf, int kb) {
        // A: 64 rows x 8 b128-chunks = 512 chunks, 2/thread
        #pragma unroll
        for (int i = 0; i < 2; ++i) {
            int c = t + i * 256;
            int r = c >> 3, c8 = c & 7;
            *(ushort8v*)&A[buf][r][c8 * 8] =
                *(const ushort8v*)&xb[(size_t)(row0 + r) * CAT + kbase + kb + c8 * 8];
        }
        // Bt: 128 rows x 8 chunks = 1024 chunks, 4/thread
        #pragma unroll
        for (int i = 0; i < 4; ++i) {
            int c = t + i * 256;
            int n = c >> 3, c8 = c & 7;
            *(ushort8v*)&Bt[buf][n][c8 * 8] =
                *(const ushort8v*)&w1t[(size_t)n * CAT + kbase + kb + c8 * 8];
        }
    };

    f32x4 acc[4][2];
    #pragma unroll
    for (int mt = 0; mt < 4; ++mt)
        #pragma unroll
        for (int nt = 0; nt < 2; ++nt)
            acc[mt][nt] = (f32x4){0.f, 0.f, 0.f, 0.f};

    stage(0, 0);
    __syncthreads();

    constexpr int NS = KSEG / 64;   // 50
    for (int s = 0; s < NS; ++s) {
        const int cur = s & 1;
        if (s + 1 < NS) stage(cur ^ 1, (s + 1) * 64);   // issue loads FIRST
        #pragma unroll
        for (int ks = 0; ks < 2; ++ks) {
            const int kcol = ks * 32 + rg * 8;
            bf16x8 bv0 = *(const bf16x8*)&Bt[cur][w * 32 + cl][kcol];
            bf16x8 bv1 = *(const bf16x8*)&Bt[cur][w * 32 + 16 + cl][kcol];
            #pragma unroll
            for (int mt = 0; mt < 4; ++mt) {
                bf16x8 a = *(const bf16x8*)&A[cur][mt * 16 + cl][kcol];
                acc[mt][0] = __builtin_amdgcn_mfma_f32_16x16x32_bf16(a, bv0, acc[mt][0], 0, 0, 0);
                acc[mt][1] = __builtin_amdgcn_mfma_f32_16x16x32_bf16(a, bv1, acc[mt][1], 0, 0, 0);
            }
        }
        __syncthreads();
    }

    // store h-partials: row = row0 + mt*16 + rg*4 + r; col = w*32 + nt*16 + cl
    #pragma unroll
    for (int mt = 0; mt < 4; ++mt) {
        #pragma unroll
        for (int nt = 0; nt < 2; ++nt) {
            #pragma unroll
            for (int r = 0; r < 4; ++r) {
                size_t row = (size_t)row0 + mt * 16 + rg * 4 + r;
                hp[((size_t)q * Btot + row) * HID + w * 32 + nt * 16 + cl] =
                    acc[mt][nt][r];
            }
        }
    }
}

// ---------------------------------------------------------------------------
// combine: h = relu(sum_q hp + b1); o = relu(h.W2 + b2); out = sigmoid(o).
// (r11-proven)  256 threads = 4 waves; 2 rows/block.
// ---------------------------------------------------------------------------
__global__ __launch_bounds__(256) void combine_sig(
    const float* __restrict__ hp, const float* __restrict__ b1,
    const float* __restrict__ W2, const float* __restrict__ b2,
    float* __restrict__ out, int Btot)
{
    __shared__ float red[4];
    const int t    = threadIdx.x;
    const int w    = t >> 6;
    const int l    = t & 63;
    const int rsel = w >> 1;
    const int col  = (w & 1) * 64 + l;
    const size_t row = (size_t)blockIdx.x * 2 + rsel;

    const float* hpr = hp + row * HID + col;
    float v = hpr[0] + hpr[(size_t)Btot * HID] + hpr[2 * (size_t)Btot * HID]
            + hpr[3 * (size_t)Btot * HID] + b1[col];
    float p = fmaxf(v, 0.f) * W2[col];
    p += __shfl_xor(p, 1,  64);
    p += __shfl_xor(p, 2,  64);
    p += __shfl_xor(p, 4,  64);
    p += __shfl_xor(p, 8,  64);
    p += __shfl_xor(p, 16, 64);
    p += __shfl_xor(p, 32, 64);
    if (l == 0) red[w] = p;
    __syncthreads();
    if (t < 2) {
        float o = red[2 * t] + red[2 * t + 1] + b2[0];
        o = fmaxf(o, 0.f);
        out[blockIdx.x * 2 + t] = 1.f / (1.f + expf(-o));
    }
}

// ---------------------------------------------------------------------------
extern "C" void kernel_launch(void* const* d_in, const int* in_sizes, int n_in,
                              void* d_out, int out_size, void* d_ws, size_t ws_size,
                              hipStream_t stream)
{
    const int*   user_idxs = (const int*)d_in[0];
    const int*   item_idxs = (const int*)d_in[1];
    const int*   user_nbt  = (const int*)d_in[2];
    const int*   item_nbt  = (const int*)d_in[3];
    const float* user_scr  = (const float*)d_in[4];
    const float* item_scr  = (const float*)d_in[5];
    const float* user_emb  = (const float*)d_in[6];
    const float* item_emb  = (const float*)d_in[7];
    const float* W1        = (const float*)d_in[8];
    const float* b1        = (const float*)d_in[9];
    const float* W2        = (const float*)d_in[10];
    const float* b2        = (const float*)d_in[11];
    float*       out       = (float*)d_out;

    const int B = in_sizes[0];      // 8192

    // ws layout (r6-proven footprint).  hp (16.8 MB) aliases us_bf (20 MB):
    // tables dead after last einsum; cvt4 rewrites them every replay.
    char* p = (char*)d_ws;
    unsigned short* w1t   = (unsigned short*)p;  p += (size_t)HID * CAT * 2;
    unsigned short* us_bf = (unsigned short*)p;  p += (size_t)in_sizes[4] * 2;
    unsigned short* is_bf = (unsigned short*)p;  p += (size_t)in_sizes[5] * 2;
    unsigned short* ue_bf = (unsigned short*)p;  p += (size_t)in_sizes[6] * 2;
    unsigned short* ie_bf = (unsigned short*)p;  p += (size_t)in_sizes[7] * 2;
    unsigned short* xb    = (unsigned short*)p;
    float*          hpb   = (float*)us_bf;       // alias (16.8 MB <= 20 MB)

    prep_w1t<<<CAT / 64, 256, 0, stream>>>(W1, w1t);
    cvt4<<<dim3(512, 4), 256, 0, stream>>>(
        user_scr, us_bf, in_sizes[4] / 4,
        item_scr, is_bf, in_sizes[5] / 4,
        user_emb, ue_bf, in_sizes[6] / 4,
        item_emb, ie_bf, in_sizes[7] / 4);

    // einsum chunked (tables L3-resident during the gather phase)
    for (int b0 = 0; b0 < B; b0 += CHUNK) {
        int rows = (B - b0 < CHUNK) ? (B - b0) : CHUNK;
        einsum_mfma<<<dim3(rows, 2), 256, 0, stream>>>(
            user_idxs, item_idxs, user_nbt, item_nbt,
            us_bf, is_bf, ue_bf, ie_bf, xb + (size_t)b0 * CAT, b0);
    }
    // MLP: K-split partials (2 blocks/CU) + combine
    mlp_kpart<<<dim3(B / 64, KSPLIT), 256, 0, stream>>>(xb, w1t, hpb, B);
    combine_sig<<<B / 2, 256, 0, stream>>>(hpb, b1, W2, b2, out, B);
}

// Round 14
// 302.642 us; speedup vs baseline: 1.4856x; 1.0045x over previous
//
#include <hip/hip_runtime.h>
#include <hip/hip_bf16.h>
#include <math.h>

constexpr int KN  = 100;            // K (multi_factor * top_k)
constexpr int DE  = 64;             // embedding dim
constexpr int CAT = 2 * KN * DE;    // 12800
constexpr int HID = 128;
constexpr int CHUNK = 4096;         // pipeline chunk: tables 49 + xb 105 +
                                    // w1t 3.3 + hp 16.8 = 174 MB < 256 MB L3
constexpr int KSPLIT = 8;
constexpr int KSEG = CAT / KSPLIT;  // 1600

typedef __bf16          bf16x8   __attribute__((ext_vector_type(8)));
typedef float           f32x4    __attribute__((ext_vector_type(4)));
typedef unsigned short  ushort8v __attribute__((ext_vector_type(8)));
typedef unsigned short  ushort4v __attribute__((ext_vector_type(4)));

static __device__ __forceinline__ unsigned short f2bf(float f) {
    __hip_bfloat16 h = __float2bfloat16(f);
    return *reinterpret_cast<unsigned short*>(&h);
}

static __device__ __forceinline__ bf16x8 mk_frag(ushort4v lo, ushort4v hi) {
    union { ushort8v u; bf16x8 b; } c;
    c.u = (ushort8v){ lo[0], lo[1], lo[2], lo[3], hi[0], hi[1], hi[2], hi[3] };
    return c.b;
}

// ---------------------------------------------------------------------------
// prep: 4 fp32->bf16 table conversions in one launch
// ---------------------------------------------------------------------------
__global__ __launch_bounds__(256) void cvt4(
    const float* __restrict__ a0, unsigned short* __restrict__ o0, int n0,
    const float* __restrict__ a1, unsigned short* __restrict__ o1, int n1,
    const float* __restrict__ a2, unsigned short* __restrict__ o2, int n2,
    const float* __restrict__ a3, unsigned short* __restrict__ o3, int n3)
{
    const float* in; unsigned short* out; int n4;
    switch (blockIdx.y) {
        case 0:  in = a0; out = o0; n4 = n0; break;
        case 1:  in = a1; out = o1; n4 = n1; break;
        case 2:  in = a2; out = o2; n4 = n2; break;
        default: in = a3; out = o3; n4 = n3; break;
    }
    for (int i = blockIdx.x * 256 + threadIdx.x; i < n4; i += gridDim.x * 256) {
        float4 v = ((const float4*)in)[i];
        ushort4v o = { f2bf(v.x), f2bf(v.y), f2bf(v.z), f2bf(v.w) };
        ((ushort4v*)out)[i] = o;
    }
}

// ---------------------------------------------------------------------------
// prep: w1t[n][k] = bf16(W1[k][n])
// ---------------------------------------------------------------------------
__global__ __launch_bounds__(256) void prep_w1t(
    const float* __restrict__ W1, unsigned short* __restrict__ w1t)
{
    __shared__ unsigned short T[HID][72];
    const int t  = threadIdx.x;
    const int k0 = blockIdx.x * 64;

    for (int idx = t; idx < 64 * HID; idx += 256) {
        int kk = idx >> 7, n = idx & 127;
        T[n][kk] = f2bf(W1[(size_t)(k0 + kk) * HID + n]);
    }
    __syncthreads();
    for (int idx = t; idx < HID * 16; idx += 256) {
        int n = idx >> 4, c4 = idx & 15;
        *(ushort4v*)&w1t[(size_t)n * CAT + k0 + c4 * 4] =
            *(const ushort4v*)&T[n][c4 * 4];
    }
}

// ---------------------------------------------------------------------------
// Kernel 1 (unchanged kernel; restored r7 CALLING PATTERN: single xb buffer
// reused per chunk so the gather tables stay L3-resident)
// ---------------------------------------------------------------------------
__global__ __launch_bounds__(256) void einsum_mfma(
    const int* __restrict__ u_idx, const int* __restrict__ i_idx,
    const int* __restrict__ u_nbt, const int* __restrict__ i_nbt,
    const unsigned short* __restrict__ u_scr, const unsigned short* __restrict__ i_scr,
    const unsigned short* __restrict__ u_emb, const unsigned short* __restrict__ i_emb,
    unsigned short* __restrict__ xb, int b0)
{
    __shared__ __align__(16) unsigned short ET[64][136];
    __shared__ int nb[KN];

    const int t    = threadIdx.x;
    const int side = blockIdx.y;
    const int b    = b0 + blockIdx.x;

    const int*            idxs = side ? i_idx : u_idx;
    const int*            nbt  = side ? i_nbt : u_nbt;
    const unsigned short* scr  = side ? i_scr : u_scr;
    const unsigned short* emb  = side ? i_emb : u_emb;

    const ushort4v z4 = {0, 0, 0, 0};

    const int center = idxs[b];
    if (t < KN) nb[t] = nbt[(size_t)center * KN + t];

    for (int idx = t; idx < 64 * 7; idx += 256) {
        int r = idx / 7, c = idx - r * 7;
        *(ushort4v*)&ET[r][100 + c * 4] = z4;
    }
    __syncthreads();                           // nb ready

    for (int idx = t; idx < 25 * 16; idx += 256) {
        int d4 = idx / 25, j0 = idx - d4 * 25;
        ushort4v v0 = *(const ushort4v*)(emb + (size_t)nb[j0 * 4 + 0] * DE + d4 * 4);
        ushort4v v1 = *(const ushort4v*)(emb + (size_t)nb[j0 * 4 + 1] * DE + d4 * 4);
        ushort4v v2 = *(const ushort4v*)(emb + (size_t)nb[j0 * 4 + 2] * DE + d4 * 4);
        ushort4v v3 = *(const ushort4v*)(emb + (size_t)nb[j0 * 4 + 3] * DE + d4 * 4);
        ushort4v o0 = { v0[0], v1[0], v2[0], v3[0] };
        ushort4v o1 = { v0[1], v1[1], v2[1], v3[1] };
        ushort4v o2 = { v0[2], v1[2], v2[2], v3[2] };
        ushort4v o3 = { v0[3], v1[3], v2[3], v3[3] };
        *(ushort4v*)&ET[d4 * 4 + 0][j0 * 4] = o0;
        *(ushort4v*)&ET[d4 * 4 + 1][j0 * 4] = o1;
        *(ushort4v*)&ET[d4 * 4 + 2][j0 * 4] = o2;
        *(ushort4v*)&ET[d4 * 4 + 3][j0 * 4] = o3;
    }
    __syncthreads();

    const int w  = t >> 6;
    const int l  = t & 63;
    const int cl = l & 15;
    const int rg = l >> 4;

    const unsigned short* srow[7];
    #pragma unroll
    for (int mt = 0; mt < 7; ++mt) {
        int kr = mt * 16 + cl;
        if (kr > KN - 1) kr = KN - 1;
        srow[mt] = scr + (size_t)nb[kr] * KN;
    }

    f32x4 acc[7];
    #pragma unroll
    for (int m = 0; m < 7; ++m) acc[m] = (f32x4){0.f, 0.f, 0.f, 0.f};

    #pragma unroll
    for (int ks = 0; ks < 4; ++ks) {
        const int k0 = ks * 32 + rg * 8;
        bf16x8 bfrag = *(const bf16x8*)&ET[w * 16 + cl][k0];
        #pragma unroll
        for (int mt = 0; mt < 7; ++mt) {
            ushort4v lo, hi;
            if (ks < 3) {
                lo = *(const ushort4v*)(srow[mt] + k0);
                hi = *(const ushort4v*)(srow[mt] + k0 + 4);
            } else if (rg == 0) {
                lo = *(const ushort4v*)(srow[mt] + 96);
                hi = z4;
            } else {
                lo = z4; hi = z4;
            }
            bf16x8 afrag = mk_frag(lo, hi);
            acc[mt] = __builtin_amdgcn_mfma_f32_16x16x32_bf16(afrag, bfrag, acc[mt], 0, 0, 0);
        }
    }
    __syncthreads();

    unsigned short* X = &ET[0][0];
    #pragma unroll
    for (int mt = 0; mt < 7; ++mt) {
        #pragma unroll
        for (int rr = 0; rr < 4; ++rr) {
            int k = mt * 16 + rg * 4 + rr;
            if (k < KN) X[k * 72 + w * 16 + cl] = f2bf(acc[mt][rr]);
        }
    }
    __syncthreads();

    unsigned short* xr = xb + (size_t)blockIdx.x * CAT + side * (KN * DE);
    for (int idx = t; idx < KN * 8; idx += 256) {
        int r = idx >> 3, c8 = idx & 7;
        *(ushort8v*)&xr[r * DE + c8 * 8] = *(const ushort8v*)&X[r * 72 + c8 * 8];
    }
}

// ---------------------------------------------------------------------------
// Kernel 2 (v14): per-chunk K-split MLP h-partials (r13 structure, KSPLIT=8).
// Grid (rows/64, 8) = 512 blocks = 2 blocks/CU.  Block = 64 rows x 128 cols
// x K-seg 1600 (25 BK=64 steps, dbuf'd coalesced A/Bt staging).  xb is
// L3-hot (written by the einsum just before).  h-partials linear in K.
// ---------------------------------------------------------------------------
__global__ __launch_bounds__(256) void mlp_kpart(
    const unsigned short* __restrict__ xb, const unsigned short* __restrict__ w1t,
    float* __restrict__ hp, int rows)
{
    __shared__ unsigned short A[2][64][72];    // 18.4 KB
    __shared__ unsigned short Bt[2][HID][72];  // 36.9 KB

    const int t  = threadIdx.x;
    const int w  = t >> 6;
    const int l  = t & 63;
    const int cl = l & 15;
    const int rg = l >> 4;
    const int row0  = blockIdx.x * 64;
    const int q     = blockIdx.y;
    const int kbase = q * KSEG;

    auto stage = [&](int buf, int kb) {
        #pragma unroll
        for (int i = 0; i < 2; ++i) {
            int c = t + i * 256;
            int r = c >> 3, c8 = c & 7;
            *(ushort8v*)&A[buf][r][c8 * 8] =
                *(const ushort8v*)&xb[(size_t)(row0 + r) * CAT + kbase + kb + c8 * 8];
        }
        #pragma unroll
        for (int i = 0; i < 4; ++i) {
            int c = t + i * 256;
            int n = c >> 3, c8 = c & 7;
            *(ushort8v*)&Bt[buf][n][c8 * 8] =
                *(const ushort8v*)&w1t[(size_t)n * CAT + kbase + kb + c8 * 8];
        }
    };

    f32x4 acc[4][2];
    #pragma unroll
    for (int mt = 0; mt < 4; ++mt)
        #pragma unroll
        for (int nt = 0; nt < 2; ++nt)
            acc[mt][nt] = (f32x4){0.f, 0.f, 0.f, 0.f};

    stage(0, 0);
    __syncthreads();

    constexpr int NS = KSEG / 64;   // 25
    for (int s = 0; s < NS; ++s) {
        const int cur = s & 1;
        if (s + 1 < NS) stage(cur ^ 1, (s + 1) * 64);   // issue loads FIRST
        #pragma unroll
        for (int ks = 0; ks < 2; ++ks) {
            const int kcol = ks * 32 + rg * 8;
            bf16x8 bv0 = *(const bf16x8*)&Bt[cur][w * 32 + cl][kcol];
            bf16x8 bv1 = *(const bf16x8*)&Bt[cur][w * 32 + 16 + cl][kcol];
            #pragma unroll
            for (int mt = 0; mt < 4; ++mt) {
                bf16x8 a = *(const bf16x8*)&A[cur][mt * 16 + cl][kcol];
                acc[mt][0] = __builtin_amdgcn_mfma_f32_16x16x32_bf16(a, bv0, acc[mt][0], 0, 0, 0);
                acc[mt][1] = __builtin_amdgcn_mfma_f32_16x16x32_bf16(a, bv1, acc[mt][1], 0, 0, 0);
            }
        }
        __syncthreads();
    }

    #pragma unroll
    for (int mt = 0; mt < 4; ++mt) {
        #pragma unroll
        for (int nt = 0; nt < 2; ++nt) {
            #pragma unroll
            for (int r = 0; r < 4; ++r) {
                size_t row = (size_t)row0 + mt * 16 + rg * 4 + r;
                hp[((size_t)q * rows + row) * HID + w * 32 + nt * 16 + cl] =
                    acc[mt][nt][r];
            }
        }
    }
}

// ---------------------------------------------------------------------------
// combine: h = relu(sum_{q<8} hp + b1); o = relu(h.W2 + b2); sigmoid.
// Fixed-order sum -> deterministic.  2 rows/block.
// ---------------------------------------------------------------------------
__global__ __launch_bounds__(256) void combine_sig(
    const float* __restrict__ hp, const float* __restrict__ b1,
    const float* __restrict__ W2, const float* __restrict__ b2,
    float* __restrict__ out, int rows)
{
    __shared__ float red[4];
    const int t    = threadIdx.x;
    const int w    = t >> 6;
    const int l    = t & 63;
    const int rsel = w >> 1;
    const int col  = (w & 1) * 64 + l;
    const size_t row = (size_t)blockIdx.x * 2 + rsel;
    const size_t qs  = (size_t)rows * HID;

    const float* hpr = hp + row * HID + col;
    float v = b1[col];
    #pragma unroll
    for (int j = 0; j < KSPLIT; ++j) v += hpr[j * qs];
    float p = fmaxf(v, 0.f) * W2[col];
    p += __shfl_xor(p, 1,  64);
    p += __shfl_xor(p, 2,  64);
    p += __shfl_xor(p, 4,  64);
    p += __shfl_xor(p, 8,  64);
    p += __shfl_xor(p, 16, 64);
    p += __shfl_xor(p, 32, 64);
    if (l == 0) red[w] = p;
    __syncthreads();
    if (t < 2) {
        float o = red[2 * t] + red[2 * t + 1] + b2[0];
        o = fmaxf(o, 0.f);
        out[blockIdx.x * 2 + t] = 1.f / (1.f + expf(-o));
    }
}

// ---------------------------------------------------------------------------
extern "C" void kernel_launch(void* const* d_in, const int* in_sizes, int n_in,
                              void* d_out, int out_size, void* d_ws, size_t ws_size,
                              hipStream_t stream)
{
    const int*   user_idxs = (const int*)d_in[0];
    const int*   item_idxs = (const int*)d_in[1];
    const int*   user_nbt  = (const int*)d_in[2];
    const int*   item_nbt  = (const int*)d_in[3];
    const float* user_scr  = (const float*)d_in[4];
    const float* item_scr  = (const float*)d_in[5];
    const float* user_emb  = (const float*)d_in[6];
    const float* item_emb  = (const float*)d_in[7];
    const float* W1        = (const float*)d_in[8];
    const float* b1        = (const float*)d_in[9];
    const float* W2        = (const float*)d_in[10];
    const float* b2        = (const float*)d_in[11];
    float*       out       = (float*)d_out;

    const int B = in_sizes[0];      // 8192

    // ws: [w1t 3.3][tables 49.2][hp 16.8][xb 105] = 174 MB  (< r6-proven 263)
    char* p = (char*)d_ws;
    unsigned short* w1t   = (unsigned short*)p;  p += (size_t)HID * CAT * 2;
    unsigned short* us_bf = (unsigned short*)p;  p += (size_t)in_sizes[4] * 2;
    unsigned short* is_bf = (unsigned short*)p;  p += (size_t)in_sizes[5] * 2;
    unsigned short* ue_bf = (unsigned short*)p;  p += (size_t)in_sizes[6] * 2;
    unsigned short* ie_bf = (unsigned short*)p;  p += (size_t)in_sizes[7] * 2;
    float*          hpb   = (float*)p;           p += (size_t)KSPLIT * CHUNK * HID * 4;
    unsigned short* xb    = (unsigned short*)p;  // CHUNK*CAT*2 = 105 MB

    prep_w1t<<<CAT / 64, 256, 0, stream>>>(W1, w1t);
    cvt4<<<dim3(512, 4), 256, 0, stream>>>(
        user_scr, us_bf, in_sizes[4] / 4,
        item_scr, is_bf, in_sizes[5] / 4,
        user_emb, ue_bf, in_sizes[6] / 4,
        item_emb, ie_bf, in_sizes[7] / 4);

    // interleaved pipeline, single xb buffer (working set L3-resident)
    for (int b0 = 0; b0 < B; b0 += CHUNK) {
        int rows = (B - b0 < CHUNK) ? (B - b0) : CHUNK;
        einsum_mfma<<<dim3(rows, 2), 256, 0, stream>>>(
            user_idxs, item_idxs, user_nbt, item_nbt,
            us_bf, is_bf, ue_bf, ie_bf, xb, b0);
        mlp_kpart<<<dim3(rows / 64, KSPLIT), 256, 0, stream>>>(
            xb, w1t, hpb, rows);
        combine_sig<<<rows / 2, 256, 0, stream>>>(
            hpb, b1, W2, b2, out + b0, rows);
    }
}